// Round 17
// baseline (77.874 us; speedup 1.0000x reference)
//
#include <hip/hip_runtime.h>
#include <hip/hip_bf16.h>

typedef float f32x4 __attribute__((ext_vector_type(4)));
typedef __bf16 bf16x8 __attribute__((ext_vector_type(8)));
typedef __bf16 bf16x4 __attribute__((ext_vector_type(4)));

__device__ __forceinline__ void gload_lds16(const __bf16* g, __bf16* l) {
  __builtin_amdgcn_global_load_lds(
      (const __attribute__((address_space(1))) void*)g,
      (__attribute__((address_space(3))) void*)l, 16, 0, 0);
}

// ---------------------------------------------------------------------------
// convert: fp32 -> bf16 for x (2M elems) and Wq/Wk/Wv/Wo (1M each)
// ---------------------------------------------------------------------------
__global__ __launch_bounds__(256) void convert_all(
    const float* __restrict__ x, const float* __restrict__ wq,
    const float* __restrict__ wk, const float* __restrict__ wv,
    const float* __restrict__ wo, __bf16* __restrict__ dst)
{
  int t = blockIdx.x * 256 + threadIdx.x;
  const float* src; size_t soff;
  if (t < 262144) { src = x; soff = (size_t)t * 8; }
  else {
    int r = (t - 262144) >> 17;
    src = (r == 0) ? wq : (r == 1) ? wk : (r == 2) ? wv : wo;
    soff = (size_t)((t - 262144) & 131071) * 8;
  }
  float4 f0 = *(const float4*)(src + soff);
  float4 f1 = *(const float4*)(src + soff + 4);
  bf16x8 o;
  o[0]=(__bf16)f0.x; o[1]=(__bf16)f0.y; o[2]=(__bf16)f0.z; o[3]=(__bf16)f0.w;
  o[4]=(__bf16)f1.x; o[5]=(__bf16)f1.y; o[6]=(__bf16)f1.z; o[7]=(__bf16)f1.w;
  *(bf16x8*)(dst + (size_t)t * 8) = o;
}

// ---------------------------------------------------------------------------
// GEMM (r16-exact): C[m][n] = sum_k A[m][k] * B[n][k].  BK=128.
// ROPE=true: z<2 -> RoPE+justnorm+sqk epilogue; z==2 -> fused V-transpose.
// ---------------------------------------------------------------------------
template <int BM, int BN, int BK, typename OutT, bool ROPE>
__global__ __launch_bounds__(256) void gemm_bt(
    const __bf16* __restrict__ A,
    const __bf16* __restrict__ B0, const __bf16* __restrict__ B1, const __bf16* __restrict__ B2,
    OutT* __restrict__ C0, OutT* __restrict__ C1, OutT* __restrict__ C2,
    int M, int N, int K, const float* __restrict__ sqkp)
{
  const __bf16* B = (blockIdx.z == 0) ? B0 : (blockIdx.z == 1) ? B1 : B2;
  OutT* C = (blockIdx.z == 0) ? C0 : (blockIdx.z == 1) ? C1 : C2;

  constexpr int MT = BM / 32, NT = BN / 32, KK = BK / 32;
  constexpr int CPR = BK / 8;
  constexpr int RPI = 64 / CPR;
  __shared__ __align__(16) __bf16 smem[BM * BK + BN * BK];
  __bf16* As = smem;
  __bf16* Bs = smem + BM * BK;

  const int tid = threadIdx.x, w = tid >> 6, l = tid & 63;
  const int wr = w >> 1, wc = w & 1;
  const int g = l >> 4, c16 = l & 15;
  const int bm = blockIdx.y, bn = blockIdx.x;
  const int lr = l / CPR, lc = l % CPR;

  f32x4 acc[MT][NT] = {};
  const int nk = K / BK;

  for (int kt = 0; kt < nk; ++kt) {
    __syncthreads();
#pragma unroll
    for (int i = w; i < BM / RPI; i += 4) {
      int row = i * RPI + lr;
      int sch = lc ^ (row & 7);
      gload_lds16(A + (size_t)(bm * BM + row) * K + kt * BK + sch * 8, As + i * RPI * BK);
    }
#pragma unroll
    for (int i = w; i < BN / RPI; i += 4) {
      int row = i * RPI + lr;
      int sch = lc ^ (row & 7);
      gload_lds16(B + (size_t)(bn * BN + row) * K + kt * BK + sch * 8, Bs + i * RPI * BK);
    }
    __syncthreads();

#pragma unroll
    for (int kk = 0; kk < KK; ++kk) {
      bf16x8 af[MT], bf[NT];
#pragma unroll
      for (int mt = 0; mt < MT; ++mt) {
        int row = wr * (BM / 2) + mt * 16 + c16;
        af[mt] = *(const bf16x8*)(As + row * BK + (((kk * 4 + g) ^ (row & 7)) * 8));
      }
#pragma unroll
      for (int nt = 0; nt < NT; ++nt) {
        int row = wc * (BN / 2) + nt * 16 + c16;
        bf[nt] = *(const bf16x8*)(Bs + row * BK + (((kk * 4 + g) ^ (row & 7)) * 8));
      }
#pragma unroll
      for (int mt = 0; mt < MT; ++mt)
#pragma unroll
        for (int nt = 0; nt < NT; ++nt)
          acc[mt][nt] = __builtin_amdgcn_mfma_f32_16x16x32_bf16(af[mt], bf[nt], acc[mt][nt], 0, 0, 0);
    }
  }

  bool done = false;
  if constexpr (ROPE) {
    static_assert(!ROPE || (NT == 4 && MT == 2), "ROPE kernel assumes BM=64, BN=128");
    if (blockIdx.z == 2) {
      // ---- fused V-transpose epilogue ----
      __syncthreads();
#pragma unroll
      for (int mt = 0; mt < MT; ++mt)
#pragma unroll
        for (int nt = 0; nt < NT; ++nt) {
          bf16x4 pk;
#pragma unroll
          for (int r = 0; r < 4; ++r) pk[r] = (__bf16)acc[mt][nt][r];
          int n0 = wr * 32 + mt * 16 + g * 4;
          int d  = nt * 16 + c16;
          *(bf16x4*)(smem + wc * 4608 + d * 72 + n0) = pk;
        }
      __syncthreads();
#pragma unroll
      for (int j = 0; j < 4; ++j) {
        int idx = tid + j * 256;
        int head = idx >> 9;
        int rem = idx & 511;
        int d = rem >> 3;
        int c8 = (rem & 7) * 8;
        bf16x8 val = *(const bf16x8*)(smem + head * 4608 + d * 72 + c8);
        *(bf16x8*)(C + (size_t)((bn * 2 + head) * 64 + d) * 2048 + bm * 64 + c8) = val;
      }
      done = true;
    } else {
      // ---- RoPE + justnorm + sqk epilogue (z<2) ----
      const bool isQ = (blockIdx.z == 0);
      const int hcol = bn * BN + wc * (BN / 2);
      float sq[4];
#pragma unroll
      for (int nt = 0; nt < 4; ++nt) sq[nt] = sqkp[hcol + nt * 16 + c16] * 32.0f;
      const float QSC = 8.0f * 1.4426950408889634f;
      const float L = 0.415241011860919f;
      const float inv0 = exp2f(-(float)c16 * L);
      const float inv1 = exp2f(-(float)(c16 + 16) * L);
#pragma unroll
      for (int mt = 0; mt < MT; ++mt) {
#pragma unroll
        for (int r = 0; r < 4; ++r) {
          int row = bm * BM + wr * (BM / 2) + mt * 16 + g * 4 + r;
          float s0, c0, s1, c1;
          sincosf((float)row * inv0, &s0, &c0);
          sincosf((float)row * inv1, &s1, &c1);
          float v0 = acc[mt][0][r], v1 = acc[mt][1][r];
          float v2 = acc[mt][2][r], v3 = acc[mt][3][r];
          float n0 = v0 * c0 - v2 * s0;
          float n2 = v0 * s0 + v2 * c0;
          float n1 = v1 * c1 - v3 * s1;
          float n3 = v1 * s1 + v3 * c1;
          float ss = n0 * n0 + n1 * n1 + n2 * n2 + n3 * n3;
#pragma unroll
          for (int m2 = 1; m2 < 16; m2 <<= 1) ss += __shfl_xor(ss, m2, 16);
          float rinv = rsqrtf(ss);
          if (isQ) rinv *= QSC;
          C[(size_t)row * N + hcol +  0 + c16] = (OutT)(n0 * sq[0] * rinv);
          C[(size_t)row * N + hcol + 16 + c16] = (OutT)(n1 * sq[1] * rinv);
          C[(size_t)row * N + hcol + 32 + c16] = (OutT)(n2 * sq[2] * rinv);
          C[(size_t)row * N + hcol + 48 + c16] = (OutT)(n3 * sq[3] * rinv);
        }
      }
      done = true;
    }
  }
  if (!done) {
#pragma unroll
    for (int mt = 0; mt < MT; ++mt)
#pragma unroll
      for (int nt = 0; nt < NT; ++nt)
#pragma unroll
        for (int r = 0; r < 4; ++r) {
          int row = bm * BM + wr * (BM / 2) + mt * 16 + g * 4 + r;
          int col = bn * BN + wc * (BN / 2) + nt * 16 + c16;
          C[(size_t)row * N + col] = (OutT)acc[mt][nt][r];
        }
  }
}

// ---------------------------------------------------------------------------
// Flash attention, KVBLK=128: one barrier pair per 128 kv (two 64-kv
// sub-steps su in {0,1}) -> chain <= 8 barrier-pairs (was 17).
// K tile: [128 rows][64 d] (row = 128B, slot XOR ^(row&7), 2-way free).
// V^T tile: [64 d][128 n] (row = 256B = 16 slots, XOR ^(row&15), 2-way free).
// Split at 128-tile granularity; merge kernel unchanged (plain addition).
// Internals otherwise r12/r16-exact (swapped QK^T, packed b64 P, lsum scalar).
// ---------------------------------------------------------------------------
#define STAGE(BUF, KT2)                                                        \
  {                                                                            \
    _Pragma("unroll")                                                          \
    for (int p = 0; p < 4; ++p) {  /* K: 128 rows x 128B */                    \
      int row = srow + p * 32;                                                 \
      int sch = sc ^ (row & 7);                                                \
      gload_lds16(Kg + (size_t)((KT2) * 128 + row) * 1024 + h * 64 + sch * 8,  \
                  &Ks[BUF][w * 512 + p * 2048]);                               \
    }                                                                          \
    _Pragma("unroll")                                                          \
    for (int p = 0; p < 4; ++p) {  /* V^T: 64 rows x 256B */                   \
      int row = srow16 + p * 16;                                               \
      int sch = sc16 ^ (row & 15);                                             \
      gload_lds16(Vg + ((size_t)h * 64 + row) * 2048 + (KT2) * 128 + sch * 8,  \
                  &Vs[BUF][w * 512 + p * 2048]);                               \
    }                                                                          \
  }

__global__ __launch_bounds__(256, 2) void attn_kernel(
    const __bf16* __restrict__ Qg, const __bf16* __restrict__ Kg,
    const __bf16* __restrict__ Vg, __bf16* __restrict__ Og,
    float* __restrict__ oS, float* __restrict__ lS)
{
  __shared__ __align__(16) __bf16 Ks[2][8192];   // 32 KB
  __shared__ __align__(16) __bf16 Vs[2][8192];   // 32 KB
  __shared__ __align__(16) __bf16 Ps[4][16 * 72];//  9 KB -> 73 KB, 2 blocks/CU

  const int b = blockIdx.x;
  int h, qt, kts2, kte2, sidx;
  if (b < 512) {
    int p = b >> 5;
    qt = 16 + p;
    sidx = (b >> 4) & 1;
    h = b & 15;
    int T = (qt + 2) >> 1;             // ceil((qt+1)/2) 128-tiles
    int T0 = T >> 1;
    kts2 = sidx ? T0 : 0;
    kte2 = sidx ? (T - 1) : (T0 - 1);
  } else {
    qt = 15 - ((b - 512) >> 4);
    h = b & 15;
    kts2 = 0; kte2 = ((qt + 2) >> 1) - 1; sidx = -1;
  }
  const int q0 = qt * 64;

  const int tid = threadIdx.x, w = tid >> 6, l = tid & 63;
  const int g = l >> 4, c16 = l & 15;
  const int srow   = tid >> 3;         // K staging: 32 rows/pass, 8 chunks
  const int sc     = tid & 7;
  const int srow16 = tid >> 4;         // V staging: 16 rows/pass, 16 chunks
  const int sc16   = tid & 15;

  __bf16* Ps_w = &Ps[w][0];
  const int qig = q0 + w * 16 + c16;   // this thread's q-row in S^T

  const __bf16* qbase = Qg + (size_t)qig * 1024 + h * 64 + g * 8;
  const bf16x8 qf0 = *(const bf16x8*)(qbase);
  const bf16x8 qf1 = *(const bf16x8*)(qbase + 32);

  f32x4 o[4] = {};
  float lsum = 0.f;

  STAGE(0, kts2)

  for (int kt2 = kts2; kt2 <= kte2; ++kt2) {
    const int cur = (kt2 - kts2) & 1;
    __syncthreads();
    if (kt2 < kte2) STAGE(cur ^ 1, kt2 + 1)

    const __bf16* Kb = Ks[cur];
    const __bf16* Vb = Vs[cur];
    const bool diag = (kt2 == ((qt >> 1)));   // 128-tile containing the diagonal

#pragma unroll
    for (int su = 0; su < 2; ++su) {
      // S^T = K Q^T : s[kjb][r] = S[qi=c16][kj = su*64 + kjb*16 + g*4 + r]
      f32x4 s[4] = {};
#pragma unroll
      for (int kjb = 0; kjb < 4; ++kjb) {
        int r = su * 64 + kjb * 16 + c16;
        bf16x8 k0 = *(const bf16x8*)((char*)Kb + r * 128 + ((g ^ (r & 7)) * 16));
        bf16x8 k1 = *(const bf16x8*)((char*)Kb + r * 128 + (((4 + g) ^ (r & 7)) * 16));
        s[kjb] = __builtin_amdgcn_mfma_f32_16x16x32_bf16(k0, qf0, s[kjb], 0, 0, 0);
        s[kjb] = __builtin_amdgcn_mfma_f32_16x16x32_bf16(k1, qf1, s[kjb], 0, 0, 0);
      }

      // P = exp2(S): packed b64 writes
#pragma unroll
      for (int kjb = 0; kjb < 4; ++kjb) {
        bf16x4 pk;
#pragma unroll
        for (int r = 0; r < 4; ++r) {
          float sv = s[kjb][r];
          int kvg = kt2 * 128 + su * 64 + kjb * 16 + g * 4 + r;
          if (diag && kvg > qig) sv = -1e30f;
          float e = exp2f(sv);
          pk[r] = (__bf16)e;
          lsum += e;
        }
        *(bf16x4*)((char*)Ps_w + c16 * 144 + kjb * 32 + g * 8) = pk;
      }

      // O += P V  (pa rows c16; V^T rows d, 256B rows, slot XOR over 16)
#pragma unroll
      for (int ks = 0; ks < 2; ++ks) {
        bf16x8 pa = *(const bf16x8*)((char*)Ps_w + c16 * 144 + ks * 64 + g * 16);
#pragma unroll
        for (int nt = 0; nt < 4; ++nt) {
          int r = nt * 16 + c16;
          int slot = (su * 8 + ks * 4 + g) ^ (r & 15);
          bf16x8 vb = *(const bf16x8*)((char*)Vb + r * 256 + slot * 16);
          o[nt] = __builtin_amdgcn_mfma_f32_16x16x32_bf16(pa, vb, o[nt], 0, 0, 0);
        }
      }
    }
  }

  // reduce lsum over the 4 g-lanes sharing q-row c16
  lsum += __shfl_xor(lsum, 16);
  lsum += __shfl_xor(lsum, 32);

  if (sidx < 0) {
    float* lsh = (float*)Ps_w;
    if (g == 0) lsh[c16] = lsum;
    __builtin_amdgcn_s_waitcnt(0);           // lgkmcnt(0): publish before read
#pragma unroll
    for (int r = 0; r < 4; ++r) {
      float rinv = 1.0f / lsh[g * 4 + r];
      int qi = q0 + w * 16 + g * 4 + r;
#pragma unroll
      for (int nt = 0; nt < 4; ++nt)
        Og[(size_t)qi * 1024 + h * 64 + nt * 16 + c16] = (__bf16)(o[nt][r] * rinv);
    }
  } else {
    float* oBase = oS + (size_t)sidx * 1024 * 1024;
#pragma unroll
    for (int r = 0; r < 4; ++r) {
      int row = q0 + w * 16 + g * 4 + r - 1024;
#pragma unroll
      for (int nt = 0; nt < 4; ++nt)
        oBase[(size_t)row * 1024 + h * 64 + nt * 16 + c16] = o[nt][r];
    }
    if (g == 0)
      lS[(size_t)sidx * 1024 * 16 + (size_t)(qig - 1024) * 16 + h] = lsum;
  }
}

// ---------------------------------------------------------------------------
// merge: rows 1024..2047: og = (oA + oB) / (lA + lB), bf16.
// ---------------------------------------------------------------------------
__global__ __launch_bounds__(256) void merge_halves(
    const float* __restrict__ oS, const float* __restrict__ lS,
    __bf16* __restrict__ Og)
{
  int row = blockIdx.x;
  int col = threadIdx.x * 4;
  int h = col >> 6;
  float lsum = lS[(size_t)row * 16 + h] + lS[(size_t)(1024 + row) * 16 + h];
  float rinv = 1.0f / lsum;
  f32x4 a = *(const f32x4*)(oS + (size_t)row * 1024 + col);
  f32x4 bb = *(const f32x4*)(oS + (size_t)(1024 * 1024) + (size_t)row * 1024 + col);
  f32x4 sum = a + bb;
  bf16x4 ob;
  ob[0] = (__bf16)(sum[0] * rinv); ob[1] = (__bf16)(sum[1] * rinv);
  ob[2] = (__bf16)(sum[2] * rinv); ob[3] = (__bf16)(sum[3] * rinv);
  *(bf16x4*)(Og + (size_t)(1024 + row) * 1024 + col) = ob;
}

// ---------------------------------------------------------------------------
extern "C" void kernel_launch(void* const* d_in, const int* in_sizes, int n_in,
                              void* d_out, int out_size, void* d_ws, size_t ws_size,
                              hipStream_t stream) {
  const float* x   = (const float*)d_in[0];
  const float* Wq  = (const float*)d_in[1];
  const float* Wk  = (const float*)d_in[2];
  const float* Wv  = (const float*)d_in[3];
  const float* Wo  = (const float*)d_in[4];
  const float* sqk = (const float*)d_in[5];
  float* out = (float*)d_out;

  __bf16* xb  = (__bf16*)d_ws;                  // [2048][1024]
  __bf16* wqb = xb  + (size_t)2048 * 1024;      // [1024][1024]
  __bf16* wkb = wqb + (size_t)1024 * 1024;
  __bf16* wvb = wkb + (size_t)1024 * 1024;
  __bf16* wob = wvb + (size_t)1024 * 1024;
  __bf16* qn  = wob + (size_t)1024 * 1024;      // [2048][1024] rope+norm'd q
  __bf16* kn  = qn  + (size_t)2048 * 1024;      // [2048][1024] rope+norm'd k
  __bf16* vtb = kn  + (size_t)2048 * 1024;      // [16][64][2048] V^T (from GEMM)
  __bf16* og  = vtb + (size_t)2048 * 1024;      // [2048][1024]
  float*  oS  = (float*)(og + (size_t)2048 * 1024);  // [2][1024][1024] f32
  float*  lS  = oS + (size_t)2 * 1024 * 1024;        // [2][1024][16]  f32

  convert_all<<<3072, 256, 0, stream>>>(x, Wq, Wk, Wv, Wo, xb);
  gemm_bt<64, 128, 128, __bf16, true><<<dim3(8, 32, 3), 256, 0, stream>>>(
      xb, wqb, wkb, wvb, qn, kn, vtb, 2048, 1024, 1024, sqk);
  attn_kernel<<<768, 256, 0, stream>>>(qn, kn, vtb, og, oS, lS);
  merge_halves<<<1024, 256, 0, stream>>>(oS, lS, og);
  gemm_bt<64, 64, 128, float, false><<<dim3(16, 32, 1), 256, 0, stream>>>(
      og, wob, wob, wob, out, out, out, 2048, 1024, 1024, nullptr);
}